// Round 5
// baseline (492.452 us; speedup 1.0000x reference)
//
#include <hip/hip_runtime.h>
#include <stdint.h>

#define M_DIM 4096
#define K_DIM 4096
#define N_DIM 11008

typedef int v4i __attribute__((ext_vector_type(4)));

// Address-space casts via uintptr_t (composable_kernel pattern).
#define LDSP(p) ((__attribute__((address_space(3))) void*)(uintptr_t)(p))
#define GLBP(p) ((__attribute__((address_space(1))) void*)(uintptr_t)(p))

// ---------------------------------------------------------------------------
// Kernel 1: per-row dynamic quantization of x (fp32 -> int8) + row scale.
// ---------------------------------------------------------------------------
__global__ __launch_bounds__(256) void quant_rows(const float* __restrict__ x,
                                                  int8_t* __restrict__ xq,
                                                  float* __restrict__ xs_out) {
    const int row = blockIdx.x;
    const int t = threadIdx.x;
    const float4* xr = (const float4*)(x + (size_t)row * K_DIM);

    float4 v[4];
    float amax = 0.0f;
#pragma unroll
    for (int r = 0; r < 4; ++r) {
        v[r] = xr[t + r * 256];
        amax = fmaxf(amax, fmaxf(fmaxf(fabsf(v[r].x), fabsf(v[r].y)),
                                 fmaxf(fabsf(v[r].z), fabsf(v[r].w))));
    }
#pragma unroll
    for (int off = 32; off > 0; off >>= 1)
        amax = fmaxf(amax, __shfl_xor(amax, off));

    __shared__ float smax[4];
    if ((t & 63) == 0) smax[t >> 6] = amax;
    __syncthreads();
    amax = fmaxf(fmaxf(smax[0], smax[1]), fmaxf(smax[2], smax[3]));

    const float xs = fmaxf(amax / 127.0f, 1e-8f);
    if (t == 0) xs_out[row] = xs;

    int* qo = (int*)(xq + (size_t)row * K_DIM);
#pragma unroll
    for (int r = 0; r < 4; ++r) {
        int q0 = (int)rintf(v[r].x / xs);
        int q1 = (int)rintf(v[r].y / xs);
        int q2 = (int)rintf(v[r].z / xs);
        int q3 = (int)rintf(v[r].w / xs);
        q0 = min(127, max(-128, q0));
        q1 = min(127, max(-128, q1));
        q2 = min(127, max(-128, q2));
        q3 = min(127, max(-128, q3));
        int packed = (q0 & 255) | ((q1 & 255) << 8) | ((q2 & 255) << 16) | (q3 << 24);
        qo[t + r * 256] = packed;
    }
}

// ---------------------------------------------------------------------------
// Kernel 2: normalize weight into contiguous int8 in workspace (unchanged).
// ---------------------------------------------------------------------------
__global__ __launch_bounds__(256) void prep_weight(const void* __restrict__ wraw,
                                                   int8_t* __restrict__ w8) {
    const int* wi = (const int*)wraw;
    int c = 0;
#pragma unroll
    for (int i = 0; i < 64; ++i) {
        int w = wi[i];
        c += (w >= -128 && w <= 127) ? 1 : 0;
    }
    const size_t tid = (size_t)blockIdx.x * 256 + threadIdx.x;  // 16 bytes each
    if (c >= 32) {
        union { int4 v; char b[16]; } o;
#pragma unroll
        for (int g = 0; g < 4; ++g) {
            int4 w = ((const int4*)wraw)[tid * 4 + g];
            o.b[g * 4 + 0] = (char)w.x;
            o.b[g * 4 + 1] = (char)w.y;
            o.b[g * 4 + 2] = (char)w.z;
            o.b[g * 4 + 3] = (char)w.w;
        }
        ((int4*)w8)[tid] = o.v;
    } else {
        ((int4*)w8)[tid] = ((const int4*)wraw)[tid];
    }
}

// ---------------------------------------------------------------------------
// Kernel 3: int8 GEMM — 256x256 tile, BK=128, A-ring(3)/B-ring(2) = 160 KiB.
// Round-5: counted-lgkmcnt discipline + spread boundary reads + early B-stage.
//
// Round-4 accounting (4744 cy/tile, 50% MfmaUtil): matrix 2340 / LDS-read
// 2304 / stage-writes ~510 -> overlap floor ~2900 cy. Residual stalls were
// wait-placement: 12-read tail pileup, late-landing B(t+1), and lgkm(0)
// draining younger reads.
//
// Per tile t (slots SA=t%3, SB=t%2; bursts: b0=(k0,i0-3)xafA, b1=(k0,i4-7)
// xafB, b2=(k1,i0-3)xafA, b3=(k1,i4-7)xafB). DS-outstanding ledger in []:
//   top:  STAGE A(t+2); issue Bk1(t)->bf[4-7], Ab1->afB   [old8 + 8]
//         lgkm(8)  -> waits Bk0(t)+Ab0(t) (issued t-1 tail)     [8]
//         BURST0
//         issue Ab2->afA                                        [12]
//         lgkm(4)  -> waits Bk1+Ab1, leaves Ab2                 [4]
//         BURST1
//   mid:  s_barrier   (every wave drained its Bk1(t) slot reads pre-b1)
//         STAGE B(t+2) -> slot t%2
//         issue Ab3->afB                                        [8]
//         lgkm(4)  -> waits Ab2, leaves Ab3                     [4]
//         BURST2
//   end:  vmcnt(8)  -> waits A(t+1)@t-1top + B(t+1)@t-1mid,
//                      leaves A(t+2)+B(t+2) in flight
//         s_barrier (publish tile t+1)
//         issue Bk0(t+1)->bf[0-3], Ab0(t+1)->afA               [12]
//         lgkm(8)  -> waits Ab3, leaves the new 8               [8]
//         BURST3
// Every read has >=1 full burst of port slack; per-phase CU port load <=768cy
// ~= one burst. Never vmcnt(0)/lgkm(0) mid-loop; tiles 30/31 peeled.
// ---------------------------------------------------------------------------
__global__ __launch_bounds__(512, 2) void w8a8_gemm(const int8_t* __restrict__ xq,
                                                    const float* __restrict__ xscale,
                                                    const int8_t* __restrict__ wgt,
                                                    const float* __restrict__ wscale,
                                                    const float* __restrict__ bias,
                                                    float* __restrict__ out) {
    __shared__ __align__(16) int8_t lds_a[3][32768];  // 96 KB: A ring, 3 tiles
    __shared__ __align__(16) int8_t lds_b[2][32768];  // 64 KB: B ring, 2 tiles

    const int t = threadIdx.x;
    const int lane = t & 63;
    const int wave = t >> 6;   // 0..7
    const int wm = wave >> 2;  // 0..1  (M half)
    const int wn = wave & 3;   // 0..3  (N quarter)
    const int quad = lane >> 4;
    const int l15 = lane & 15;

    // XCD-aware swizzle, bm-fastest within chunk (688 = 8 XCDs x 86).
    const int wg = blockIdx.x;
    const int xcd = wg & 7;
    const int u = wg >> 3;              // 0..85 within XCD
    const int bm = 2 * xcd + (u & 1);   // each XCD owns a bm pair
    const int bn = u >> 1;              // 0..42

    const int8_t* pa = xq + (size_t)bm * 256 * K_DIM;
    const int8_t* pb = wgt + (size_t)bn * 256 * K_DIM;

    // Staging: thread t covers (row = g*64 + (t>>3), 16B-chunk = t&7); source
    // chunk pre-XOR'd so linear LDS write + XOR'd read = swizzle.
    const int srow = t >> 3;  // 0..63
    const size_t soff = (size_t)srow * K_DIM + (size_t)(((t & 7) ^ (srow & 7)) << 4);
    const size_t g64 = (size_t)64 * K_DIM;  // +64 rows

#define STAGE_TILE(gb, lb)                                                                   \
    do {                                                                                     \
        __builtin_amdgcn_global_load_lds(GLBP((gb) + soff), LDSP((lb) + t * 16), 16, 0, 0);  \
        __builtin_amdgcn_global_load_lds(GLBP((gb) + soff + g64), LDSP((lb) + 8192 + t * 16), 16, 0, 0); \
        __builtin_amdgcn_global_load_lds(GLBP((gb) + soff + 2 * g64), LDSP((lb) + 16384 + t * 16), 16, 0, 0); \
        __builtin_amdgcn_global_load_lds(GLBP((gb) + soff + 3 * g64), LDSP((lb) + 24576 + t * 16), 16, 0, 0); \
    } while (0)

    // Fragment read offsets: row*128 + ((ks*4+quad) ^ (row&7))*16.
    int abase[2], bbase[2];
#pragma unroll
    for (int ks = 0; ks < 2; ++ks) {
        const int ar = wm * 128 + l15;
        abase[ks] = ar * 128 + (((ks * 4 + quad) ^ (l15 & 7)) << 4);
        const int br = wn * 64 + l15;
        bbase[ks] = br * 128 + (((ks * 4 + quad) ^ (l15 & 7)) << 4);
    }

    v4i acc[8][4] = {};
    v4i afA[4], afB[4], bf[8];  // bf[0-3]=Bk0, bf[4-7]=Bk1 of current tile

#define ISSUE_B4(SB, KS, B0)                                          \
    _Pragma("unroll") for (int j = 0; j < 4; ++j)                     \
        bf[(B0) + j] = *(const v4i*)(&lds_b[SB][bbase[KS] + j * 2048]);
#define ISSUE_A4(DST, SA, KS, I0)                                     \
    _Pragma("unroll") for (int i = 0; i < 4; ++i)                     \
        DST[i] = *(const v4i*)(&lds_a[SA][abase[KS] + ((I0) + i) * 2048]);
#define MFMA4(AF, B0, R0)                                             \
    __builtin_amdgcn_s_setprio(1);                                    \
    _Pragma("unroll") for (int i = 0; i < 4; ++i)                     \
    _Pragma("unroll") for (int j = 0; j < 4; ++j)                     \
        acc[(R0) + i][j] = __builtin_amdgcn_mfma_i32_16x16x64_i8(     \
            AF[i], bf[(B0) + j], acc[(R0) + i][j], 0, 0, 0);          \
    __builtin_amdgcn_s_setprio(0);
#define LGKM(n)                                                       \
    asm volatile("s_waitcnt lgkmcnt(" #n ")" ::: "memory");           \
    __builtin_amdgcn_sched_barrier(0);

    // ---- prologue: stage tiles 0,1 (A slots 0,1 / B slots 0,1) ----
    STAGE_TILE(pa, &lds_a[0][0]);
    STAGE_TILE(pb, &lds_b[0][0]);
    STAGE_TILE(pa + 128, &lds_a[1][0]);
    STAGE_TILE(pb + 128, &lds_b[1][0]);
    asm volatile("s_waitcnt vmcnt(8)" ::: "memory");  // tile 0 (oldest 8) landed
    __builtin_amdgcn_s_barrier();
    ISSUE_B4(0, 0, 0);       // Bk0(0) -> bf[0-3]
    ISSUE_A4(afA, 0, 0, 0);  // Ab0(0)
    // no wait here: tile 0's top LGKM(8) covers these.

#define DO_TILE(U)                                                       \
    {                                                                    \
        constexpr int SA = (U) % 3;                                      \
        constexpr int SB = (U) % 2;                                      \
        constexpr int SA1 = ((U) + 1) % 3;                               \
        constexpr int SB1 = ((U) + 1) % 2;                               \
        constexpr int SA2 = ((U) + 2) % 3;                               \
        const size_t k2 = (size_t)(t0 + (U) + 2) * 128;                  \
        /* --- top --- */                                                \
        STAGE_TILE(pa + k2, &lds_a[SA2][0]);                             \
        ISSUE_B4(SB, 1, 4);       /* Bk1(t) */                           \
        ISSUE_A4(afB, SA, 0, 4);  /* Ab1 */                              \
        LGKM(8);                  /* waits Bk0(t)+Ab0(t) */              \
        MFMA4(afA, 0, 0);         /* burst0 */                           \
        ISSUE_A4(afA, SA, 1, 0);  /* Ab2 */                              \
        LGKM(4);                  /* waits Bk1+Ab1 */                    \
        MFMA4(afB, 0, 4);         /* burst1 */                           \
        /* --- mid --- */                                                \
        __builtin_amdgcn_s_barrier();                                    \
        STAGE_TILE(pb + k2, &lds_b[SB][0]);                              \
        ISSUE_A4(afB, SA, 1, 4);  /* Ab3 */                              \
        LGKM(4);                  /* waits Ab2 */                        \
        MFMA4(afA, 4, 0);         /* burst2 */                           \
        /* --- end --- */                                                \
        asm volatile("s_waitcnt vmcnt(8)" ::: "memory");                 \
        __builtin_amdgcn_s_barrier();                                    \
        ISSUE_B4(SB1, 0, 0);      /* Bk0(t+1) */                         \
        ISSUE_A4(afA, SA1, 0, 0); /* Ab0(t+1) */                         \
        LGKM(8);                  /* waits Ab3 */                        \
        MFMA4(afB, 4, 4);         /* burst3 */                           \
    }

    // 32 K-tiles; loop covers t = 0..29 (max staged tile index = 31),
    // tiles 30,31 peeled with no stages.
#pragma unroll 1
    for (int t0 = 0; t0 < 30; t0 += 6) {
        DO_TILE(0)
        DO_TILE(1)
        DO_TILE(2)
        DO_TILE(3)
        DO_TILE(4)
        DO_TILE(5)
    }
    // ---- tile 30 (SA=0, SB=0, SA1=1, SB1=1): no stages ----
    ISSUE_B4(0, 1, 4);       // Bk1(30)
    ISSUE_A4(afB, 0, 0, 4);  // Ab1
    LGKM(8);
    MFMA4(afA, 0, 0);
    ISSUE_A4(afA, 0, 1, 0);  // Ab2
    LGKM(4);
    MFMA4(afB, 0, 4);
    ISSUE_A4(afB, 0, 1, 4);  // Ab3
    LGKM(4);
    MFMA4(afA, 4, 0);
    asm volatile("s_waitcnt vmcnt(0)" ::: "memory");  // A(31)+B(31) landed
    __builtin_amdgcn_s_barrier();
    ISSUE_B4(1, 0, 0);       // Bk0(31)
    ISSUE_A4(afA, 1, 0, 0);  // Ab0(31)
    LGKM(8);                 // waits Ab3(30)
    MFMA4(afB, 4, 4);
    // ---- tile 31 (SA=1, SB=1): final ----
    ISSUE_B4(1, 1, 4);       // Bk1(31)
    ISSUE_A4(afB, 1, 0, 4);  // Ab1
    LGKM(8);
    MFMA4(afA, 0, 0);
    ISSUE_A4(afA, 1, 1, 0);  // Ab2
    LGKM(4);
    MFMA4(afB, 0, 4);
    ISSUE_A4(afB, 1, 1, 4);  // Ab3
    LGKM(4);
    MFMA4(afA, 4, 0);
    LGKM(0);
    MFMA4(afB, 4, 4);

    // --- epilogue: dequant + bias (unchanged math/layout) ---
    float wsc[4], bi[4];
#pragma unroll
    for (int j = 0; j < 4; ++j) {
        const int cc = bn * 256 + wn * 64 + j * 16 + l15;
        wsc[j] = wscale[cc];
        bi[j] = bias[cc];
    }
#pragma unroll
    for (int i = 0; i < 8; ++i) {
        const int m0 = bm * 256 + wm * 128 + i * 16 + quad * 4;  // 4-aligned
        const float4 xs4 = *(const float4*)(xscale + m0);
        const float xsv[4] = {xs4.x, xs4.y, xs4.z, xs4.w};
#pragma unroll
        for (int r = 0; r < 4; ++r) {
            const size_t off = (size_t)(m0 + r) * N_DIM + (size_t)bn * 256 + wn * 64 + l15;
#pragma unroll
            for (int j = 0; j < 4; ++j) {
                out[off + j * 16] = (float)acc[i][j][r] * xsv[r] * wsc[j] + bi[j];
            }
        }
    }
}

// ---------------------------------------------------------------------------
extern "C" void kernel_launch(void* const* d_in, const int* in_sizes, int n_in,
                              void* d_out, int out_size, void* d_ws, size_t ws_size,
                              hipStream_t stream) {
    const float* x = (const float*)d_in[0];
    const void* wraw = (const void*)d_in[1];
    const float* wscale = (const float*)d_in[2];
    const float* bias = (const float*)d_in[3];
    float* out = (float*)d_out;

    // workspace layout: [w8: N*K][xq: M*K][xs: M floats]
    int8_t* w8 = (int8_t*)d_ws;
    int8_t* xq = (int8_t*)d_ws + (size_t)N_DIM * K_DIM;
    float* xs = (float*)((char*)d_ws + (size_t)N_DIM * K_DIM + (size_t)M_DIM * K_DIM);

    quant_rows<<<M_DIM, 256, 0, stream>>>(x, xq, xs);
    prep_weight<<<(N_DIM * (K_DIM / 16)) / 256, 256, 0, stream>>>(wraw, w8);
    // 256x256 tiles: 16 x 43 = 688 blocks (1-D, XCD-swizzled)
    w8a8_gemm<<<688, 512, 0, stream>>>(xq, xs, w8, wscale, bias, out);
}